// Round 11
// baseline (135.587 us; speedup 1.0000x reference)
//
#include <hip/hip_runtime.h>

// Bidirectional Chamfer loss — R11 MEASUREMENT ROUND.
// Structure = R7/R10 baseline (best: 24.3 us). Each kernel's hot section
// is wrapped in an idempotent repeat loop (REP_C/REP_R/REP_F) with asm
// anti-CSE barriers, inflating it above the harness's ~40us poison fills
// so rocprof's top-5 finally shows OUR kernels with counters. Results are
// bit-identical to REP=1 (recomputed identical mins/sums; single store).
// Next round: REP->1 and act on the measured breakdown.

#define CHUNK  64     // targets per block tile (1 KB in LDS)
#define QPT    8      // query points per thread
#define BIGF   3.4e38f

#define REP_C  8      // chamfer scan repeats
#define REP_R  48     // reduce body repeats
#define REP_F  64     // final body repeats

// ws layout (floats):
//  dir1 partials [b][ch][q] : 4 x 32 x 8192 = 1,048,576
//  dir2 partials [b][ch][q] : 4 x 128 x 2048 = 1,048,576 (at P2_OFF)
//  psum: RBLOCKS floats at PSUM_OFF
#define P2_OFF   1048576
#define PSUM_OFF 2097152
#define RBLOCKS  640

__global__ __launch_bounds__(256) void chamfer_kernel(
    const float* __restrict__ shape,  // [4, 8192, 3]
    const float* __restrict__ skel,   // [4, 2048, 3]
    float* __restrict__ pw)           // partial mins
{
    const int b   = blockIdx.y;
    const int tid = threadIdx.x;

    // 256 tiles/batch: dir1 = 4 qb x 32 ch, dir2 = 1 qb x 128 ch.
    const float* q; const float* t; float* pbase;
    int nq, mt, qb, ch;
    int x = blockIdx.x;
    if (x < 128) {                    // dir1: shape -> skel
        q = shape; t = skel; nq = 8192; mt = 2048;
        qb = x >> 5; ch = x & 31;
        pbase = pw + ((size_t)b * 32 + ch) * 8192;
    } else {                          // dir2: skel -> shape
        x -= 128;
        q = skel; t = shape; nq = 2048; mt = 8192;
        qb = 0; ch = x;
        pbase = pw + P2_OFF + ((size_t)b * 128 + ch) * 2048;
    }

    __shared__ float4 lds[CHUNK];

    // Stage CHUNK targets as (x, y, z, |t|^2).
    if (tid < CHUNK) {
        const float* tb = t + ((size_t)b * mt + ch * CHUNK) * 3;
        float tx = tb[tid * 3 + 0], ty = tb[tid * 3 + 1], tz = tb[tid * 3 + 2];
        lds[tid] = make_float4(tx, ty, tz, tx * tx + ty * ty + tz * tz);
    }

    // My QPT query points: precompute -2q and |q|^2.
    const int q0 = qb * 2048 + tid;               // queries q0 + k*256
    const float* qp = q + ((size_t)b * nq + q0) * 3;
    float nqx[QPT], nqy[QPT], nqz[QPT], qsq[QPT], mn[QPT];
    #pragma unroll
    for (int k = 0; k < QPT; ++k) {
        float xq = qp[k * 768 + 0];               // 768 = 256 pts * 3
        float yq = qp[k * 768 + 1];
        float zq = qp[k * 768 + 2];
        nqx[k] = -2.0f * xq; nqy[k] = -2.0f * yq; nqz[k] = -2.0f * zq;
        qsq[k] = xq * xq + yq * yq + zq * zq;
        mn[k]  = BIGF;
    }

    __syncthreads();

    // Hot scan, repeated REP_C times (idempotent: min over same set).
    int jb = 0;                                   // opaque base to defeat CSE
    #pragma unroll 1
    for (int rep = 0; rep < REP_C; ++rep) {
        asm volatile("" : "+v"(jb));
        #pragma unroll
        for (int k = 0; k < QPT; ++k) asm volatile("" : "+v"(mn[k]));
        #pragma unroll 4
        for (int j = 0; j < CHUNK; j += 2) {
            float4 ta = lds[jb + j + 0];          // broadcast: conflict-free
            float4 tb = lds[jb + j + 1];
            #pragma unroll
            for (int k = 0; k < QPT; ++k) {
                float e0 = fmaf(nqx[k], ta.x,
                           fmaf(nqy[k], ta.y,
                           fmaf(nqz[k], ta.z, ta.w)));
                float e1 = fmaf(nqx[k], tb.x,
                           fmaf(nqy[k], tb.y,
                           fmaf(nqz[k], tb.z, tb.w)));
                mn[k] = fminf(fminf(mn[k], e0), e1);  // v_min3_f32
            }
        }
    }

    // One coalesced store per (query, chunk) partial — no atomics.
    #pragma unroll
    for (int k = 0; k < QPT; ++k)
        pbase[q0 + k * 256] = qsq[k] + mn[k];
}

// 640 blocks: 64 queries/block, 4 lanes per query split over chunks.
// Blocks 0..511 = dir1 (32 chunks), 512..639 = dir2 (128 chunks).
__global__ __launch_bounds__(256) void reduce_kernel(
    const float* __restrict__ pw, float* __restrict__ psum)
{
    const int blk = blockIdx.x, tid = threadIdx.x;
    const int sub = tid & 3, qi = tid >> 2;       // 4 lanes per query

    float m = BIGF;
    int ib = 0;                                   // opaque base to defeat CSE
    #pragma unroll 1
    for (int rep = 0; rep < REP_R; ++rep) {
        asm volatile("" : "+v"(ib));
        m = BIGF;
        if (blk < 512) {                          // dir1: 8 loads/lane
            const int b  = blk >> 7;
            const int ql = ((blk & 127) << 6) + qi;
            const float* p = pw + (size_t)b * 32 * 8192 + ql;
            #pragma unroll
            for (int i = 0; i < 8; ++i)
                m = fminf(m, p[ib + (sub * 8 + i) * 8192]);
        } else {                                  // dir2: 32 loads/lane
            const int z  = blk - 512;
            const int b  = z >> 5;
            const int ql = ((z & 31) << 6) + qi;
            const float* p = pw + P2_OFF + (size_t)b * 128 * 2048 + ql;
            #pragma unroll
            for (int i = 0; i < 32; ++i)
                m = fminf(m, p[ib + (sub * 32 + i) * 2048]);
        }
    }

    // Min across the 4-lane group, clamp, keep one copy.
    m = fminf(m, __shfl_xor(m, 1));
    m = fminf(m, __shfl_xor(m, 2));
    float s = (sub == 0) ? fmaxf(m, 0.0f) : 0.0f;

    // Wave + block sum.
    #pragma unroll
    for (int off = 32; off > 0; off >>= 1)
        s += __shfl_down(s, off);

    __shared__ float wsum[4];
    const int lane = tid & 63, w = tid >> 6;
    if (lane == 0) wsum[w] = s;
    __syncthreads();
    if (tid == 0) psum[blk] = (wsum[0] + wsum[1]) + (wsum[2] + wsum[3]);
}

__global__ __launch_bounds__(256) void final_kernel(
    const float* __restrict__ psum, float* __restrict__ out)
{
    float s = 0.0f;
    int ib = 0;                                   // opaque base to defeat CSE
    #pragma unroll 1
    for (int rep = 0; rep < REP_F; ++rep) {
        asm volatile("" : "+v"(ib));
        s = psum[ib + threadIdx.x] + psum[ib + threadIdx.x + 256];
        if (threadIdx.x < 128) s += psum[ib + threadIdx.x + 512];
    }

    #pragma unroll
    for (int off = 32; off > 0; off >>= 1)
        s += __shfl_down(s, off);

    __shared__ float wsum[4];
    const int lane = threadIdx.x & 63, w = threadIdx.x >> 6;
    if (lane == 0) wsum[w] = s;
    __syncthreads();
    if (threadIdx.x == 0)
        out[0] = ((wsum[0] + wsum[1]) + (wsum[2] + wsum[3])) * 1.0e-4f;
}

extern "C" void kernel_launch(void* const* d_in, const int* in_sizes, int n_in,
                              void* d_out, int out_size, void* d_ws, size_t ws_size,
                              hipStream_t stream) {
    const float* shape = (const float*)d_in[0];   // [4, 8192, 3]
    const float* skel  = (const float*)d_in[1];   // [4, 2048, 3]
    float* out         = (float*)d_out;           // scalar f32
    float* pw          = (float*)d_ws;

    // 256 tiles/batch x 4 batches = 1024 blocks (4/CU, 4 waves/SIMD).
    chamfer_kernel<<<dim3(256, 4), 256, 0, stream>>>(shape, skel, pw);

    // 640 blocks, then tiny deterministic final sum.
    reduce_kernel<<<RBLOCKS, 256, 0, stream>>>(pw, pw + PSUM_OFF);
    final_kernel<<<1, 256, 0, stream>>>(pw + PSUM_OFF, out);
}

// Round 12
// 28.971 us; speedup vs baseline: 4.6801x; 4.6801x over previous
//
#include <hip/hip_runtime.h>

// Bidirectional Chamfer loss, fused:
//   out = 1e-4 * ( sum_n min_m |shape[b,n]-skel[b,m]|^2
//                + sum_m min_n |skel[b,m]-shape[b,n]|^2 )
//
// R12: R11 measurement showed chamfer = 11.1us/scan = VALU(6.0) + LDS(5.1)
// SUMMED — broadcast ds_read_b128 doesn't overlap with VALU. Fix: targets
// are wave-uniform, so read them via uniform global indices -> compiler
// emits s_load into SGPRs (scalar pipe). LDS/staging/syncthreads deleted.
// Inner loop: per target 3 FMA (1 SGPR src each) + per-pair min3; tsq
// computed once per target in VALU. Reduce/final identical to R7.

#define CHUNK  64     // targets per tile
#define QPT    8      // query points per thread
#define BIGF   3.4e38f

// ws layout (floats):
//  dir1 partials [b][ch][q] : 4 x 32 x 8192 = 1,048,576
//  dir2 partials [b][ch][q] : 4 x 128 x 2048 = 1,048,576 (at P2_OFF)
//  psum: RBLOCKS floats at PSUM_OFF
#define P2_OFF   1048576
#define PSUM_OFF 2097152
#define RBLOCKS  640

__global__ __launch_bounds__(256) void chamfer_kernel(
    const float* __restrict__ shape,  // [4, 8192, 3]
    const float* __restrict__ skel,   // [4, 2048, 3]
    float* __restrict__ pw)           // partial mins
{
    const int b   = blockIdx.y;
    const int tid = threadIdx.x;

    // 256 tiles/batch: dir1 = 4 qb x 32 ch, dir2 = 1 qb x 128 ch.
    const float* q; const float* t; float* pbase;
    int nq, mt, qb, ch;
    int x = blockIdx.x;
    if (x < 128) {                    // dir1: shape -> skel
        q = shape; t = skel; nq = 8192; mt = 2048;
        qb = x >> 5; ch = x & 31;
        pbase = pw + ((size_t)b * 32 + ch) * 8192;
    } else {                          // dir2: skel -> shape
        x -= 128;
        q = skel; t = shape; nq = 2048; mt = 8192;
        qb = 0; ch = x;
        pbase = pw + P2_OFF + ((size_t)b * 128 + ch) * 2048;
    }

    // Wave-uniform target base (blockIdx-only) -> scalar loads.
    const float* __restrict__ tb = t + ((size_t)b * mt + ch * CHUNK) * 3;

    // My QPT query points: precompute -2q and |q|^2.
    const int q0 = qb * 2048 + tid;               // queries q0 + k*256
    const float* qp = q + ((size_t)b * nq + q0) * 3;
    float nqx[QPT], nqy[QPT], nqz[QPT], qsq[QPT], mn[QPT];
    #pragma unroll
    for (int k = 0; k < QPT; ++k) {
        float xq = qp[k * 768 + 0];               // 768 = 256 pts * 3
        float yq = qp[k * 768 + 1];
        float zq = qp[k * 768 + 2];
        nqx[k] = -2.0f * xq; nqy[k] = -2.0f * yq; nqz[k] = -2.0f * zq;
        qsq[k] = xq * xq + yq * yq + zq * zq;
        mn[k]  = BIGF;
    }

    // Pure-VALU inner loop; targets arrive via s_load (scalar pipe).
    // Per 2 targets & query: 6 FMA + 1 v_min3_f32; + 3 VALU/target for tsq.
    #pragma unroll 4
    for (int j = 0; j < CHUNK; j += 2) {
        const float tax = tb[(j + 0) * 3 + 0];    // uniform -> SGPR
        const float tay = tb[(j + 0) * 3 + 1];
        const float taz = tb[(j + 0) * 3 + 2];
        const float tbx = tb[(j + 1) * 3 + 0];
        const float tby = tb[(j + 1) * 3 + 1];
        const float tbz = tb[(j + 1) * 3 + 2];
        // |t|^2 in VGPR (v_mul s,s + 2 v_fma, 1 unique SGPR each).
        const float tasq = tax * tax + tay * tay + taz * taz;
        const float tbsq = tbx * tbx + tby * tby + tbz * tbz;
        #pragma unroll
        for (int k = 0; k < QPT; ++k) {
            float e0 = fmaf(nqx[k], tax,
                       fmaf(nqy[k], tay,
                       fmaf(nqz[k], taz, tasq)));
            float e1 = fmaf(nqx[k], tbx,
                       fmaf(nqy[k], tby,
                       fmaf(nqz[k], tbz, tbsq)));
            mn[k] = fminf(fminf(mn[k], e0), e1);  // v_min3_f32
        }
    }

    // One coalesced store per (query, chunk) partial — no atomics.
    #pragma unroll
    for (int k = 0; k < QPT; ++k)
        pbase[q0 + k * 256] = qsq[k] + mn[k];
}

// 640 blocks: 64 queries/block, 4 lanes per query split over chunks.
// Blocks 0..511 = dir1 (32 chunks), 512..639 = dir2 (128 chunks).
__global__ __launch_bounds__(256) void reduce_kernel(
    const float* __restrict__ pw, float* __restrict__ psum)
{
    const int blk = blockIdx.x, tid = threadIdx.x;
    const int sub = tid & 3, qi = tid >> 2;       // 4 lanes per query

    float m = BIGF;
    if (blk < 512) {                              // dir1: 8 loads/lane
        const int b  = blk >> 7;
        const int ql = ((blk & 127) << 6) + qi;
        const float* p = pw + (size_t)b * 32 * 8192 + ql;
        #pragma unroll
        for (int i = 0; i < 8; ++i)
            m = fminf(m, p[(sub * 8 + i) * 8192]);
    } else {                                      // dir2: 32 loads/lane
        const int z  = blk - 512;
        const int b  = z >> 5;
        const int ql = ((z & 31) << 6) + qi;
        const float* p = pw + P2_OFF + (size_t)b * 128 * 2048 + ql;
        #pragma unroll
        for (int i = 0; i < 32; ++i)
            m = fminf(m, p[(sub * 32 + i) * 2048]);
    }

    // Min across the 4-lane group, clamp, keep one copy.
    m = fminf(m, __shfl_xor(m, 1));
    m = fminf(m, __shfl_xor(m, 2));
    float s = (sub == 0) ? fmaxf(m, 0.0f) : 0.0f;

    // Wave + block sum.
    #pragma unroll
    for (int off = 32; off > 0; off >>= 1)
        s += __shfl_down(s, off);

    __shared__ float wsum[4];
    const int lane = tid & 63, w = tid >> 6;
    if (lane == 0) wsum[w] = s;
    __syncthreads();
    if (tid == 0) psum[blk] = (wsum[0] + wsum[1]) + (wsum[2] + wsum[3]);
}

__global__ __launch_bounds__(256) void final_kernel(
    const float* __restrict__ psum, float* __restrict__ out)
{
    float s = psum[threadIdx.x] + psum[threadIdx.x + 256];
    if (threadIdx.x < 128) s += psum[threadIdx.x + 512];

    #pragma unroll
    for (int off = 32; off > 0; off >>= 1)
        s += __shfl_down(s, off);

    __shared__ float wsum[4];
    const int lane = threadIdx.x & 63, w = threadIdx.x >> 6;
    if (lane == 0) wsum[w] = s;
    __syncthreads();
    if (threadIdx.x == 0)
        out[0] = ((wsum[0] + wsum[1]) + (wsum[2] + wsum[3])) * 1.0e-4f;
}

extern "C" void kernel_launch(void* const* d_in, const int* in_sizes, int n_in,
                              void* d_out, int out_size, void* d_ws, size_t ws_size,
                              hipStream_t stream) {
    const float* shape = (const float*)d_in[0];   // [4, 8192, 3]
    const float* skel  = (const float*)d_in[1];   // [4, 2048, 3]
    float* out         = (float*)d_out;           // scalar f32
    float* pw          = (float*)d_ws;

    // 256 tiles/batch x 4 batches = 1024 blocks (4/CU, 4 waves/SIMD).
    chamfer_kernel<<<dim3(256, 4), 256, 0, stream>>>(shape, skel, pw);

    // 640 blocks, then tiny deterministic final sum.
    reduce_kernel<<<RBLOCKS, 256, 0, stream>>>(pw, pw + PSUM_OFF);
    final_kernel<<<1, 256, 0, stream>>>(pw + PSUM_OFF, out);
}

// Round 13
// 26.082 us; speedup vs baseline: 5.1985x; 1.1108x over previous
//
#include <hip/hip_runtime.h>

// Bidirectional Chamfer loss, fused:
//   out = 1e-4 * ( sum_n min_m |shape[b,n]-skel[b,m]|^2
//                + sum_m min_n |skel[b,m]-shape[b,n]|^2 )
//
// R13: R11 measured chamfer = VALU(6.0us) + LDS(5.1us) SUMMED (phase-locked
// waves alternate pipes; R10 showed it's not latency). R12's s_load path
// serialized on lgkmcnt drains (+4.7us). This round: NO LDS, NO s_load —
// targets read as vector global_load_dwordx4 (wave-uniform address kept in
// a VGPR via opaque-zero asm so the compiler can't scalarize). 4 targets =
// exactly 3 aligned float4s; VMEM overlaps VALU via counted vmcnt.
// tsq computed in-register. Reduce/final identical to R7 (best base).

#define CHUNK  64     // targets per tile (16 groups of 4)
#define QPT    8      // query points per thread
#define BIGF   3.4e38f

// ws layout (floats):
//  dir1 partials [b][ch][q] : 4 x 32 x 8192 = 1,048,576
//  dir2 partials [b][ch][q] : 4 x 128 x 2048 = 1,048,576 (at P2_OFF)
//  psum: RBLOCKS floats at PSUM_OFF
#define P2_OFF   1048576
#define PSUM_OFF 2097152
#define RBLOCKS  640

__global__ __launch_bounds__(256) void chamfer_kernel(
    const float* __restrict__ shape,  // [4, 8192, 3]
    const float* __restrict__ skel,   // [4, 2048, 3]
    float* __restrict__ pw)           // partial mins
{
    const int b   = blockIdx.y;
    const int tid = threadIdx.x;

    // 256 tiles/batch: dir1 = 4 qb x 32 ch, dir2 = 1 qb x 128 ch.
    const float* q; const float* t; float* pbase;
    int nq, mt, qb, ch;
    int x = blockIdx.x;
    if (x < 128) {                    // dir1: shape -> skel
        q = shape; t = skel; nq = 8192; mt = 2048;
        qb = x >> 5; ch = x & 31;
        pbase = pw + ((size_t)b * 32 + ch) * 8192;
    } else {                          // dir2: skel -> shape
        x -= 128;
        q = skel; t = shape; nq = 2048; mt = 8192;
        qb = 0; ch = x;
        pbase = pw + P2_OFF + ((size_t)b * 128 + ch) * 2048;
    }

    // Opaque zero in a VGPR: forces the target loads to stay VECTOR
    // (global_load_dwordx4) instead of being scalarized into s_load.
    int zr = 0;
    asm volatile("" : "+v"(zr));

    // Chunk base: 64 targets x 3 floats = 48 float4s, 16B-aligned.
    const float4* __restrict__ tb4 =
        (const float4*)(t + ((size_t)b * mt + ch * CHUNK) * 3) + zr;

    // My QPT query points: precompute -2q and |q|^2.
    const int q0 = qb * 2048 + tid;               // queries q0 + k*256
    const float* qp = q + ((size_t)b * nq + q0) * 3;
    float nqx[QPT], nqy[QPT], nqz[QPT], qsq[QPT], mn[QPT];
    #pragma unroll
    for (int k = 0; k < QPT; ++k) {
        float xq = qp[k * 768 + 0];               // 768 = 256 pts * 3
        float yq = qp[k * 768 + 1];
        float zq = qp[k * 768 + 2];
        nqx[k] = -2.0f * xq; nqy[k] = -2.0f * yq; nqz[k] = -2.0f * zq;
        qsq[k] = xq * xq + yq * yq + zq * zq;
        mn[k]  = BIGF;
    }

    // 16 groups of 4 targets; each group = 3 float4 loads (one line each),
    // 12 VALU for tsq, then 8 queries x 4 targets: 12 FMA + 2 min3 each.
    #pragma unroll 4
    for (int g = 0; g < CHUNK / 4; ++g) {
        float4 v0 = tb4[g * 3 + 0];               // x0 y0 z0 x1
        float4 v1 = tb4[g * 3 + 1];               // y1 z1 x2 y2
        float4 v2 = tb4[g * 3 + 2];               // z2 x3 y3 z3
        const float s0 = fmaf(v0.x, v0.x, fmaf(v0.y, v0.y, v0.z * v0.z));
        const float s1 = fmaf(v0.w, v0.w, fmaf(v1.x, v1.x, v1.y * v1.y));
        const float s2 = fmaf(v1.z, v1.z, fmaf(v1.w, v1.w, v2.x * v2.x));
        const float s3 = fmaf(v2.y, v2.y, fmaf(v2.z, v2.z, v2.w * v2.w));
        #pragma unroll
        for (int k = 0; k < QPT; ++k) {
            float e0 = fmaf(nqx[k], v0.x, fmaf(nqy[k], v0.y, fmaf(nqz[k], v0.z, s0)));
            float e1 = fmaf(nqx[k], v0.w, fmaf(nqy[k], v1.x, fmaf(nqz[k], v1.y, s1)));
            float e2 = fmaf(nqx[k], v1.z, fmaf(nqy[k], v1.w, fmaf(nqz[k], v2.x, s2)));
            float e3 = fmaf(nqx[k], v2.y, fmaf(nqy[k], v2.z, fmaf(nqz[k], v2.w, s3)));
            mn[k] = fminf(fminf(mn[k], e0), e1);  // v_min3_f32
            mn[k] = fminf(fminf(mn[k], e2), e3);  // v_min3_f32
        }
    }

    // One coalesced store per (query, chunk) partial — no atomics.
    #pragma unroll
    for (int k = 0; k < QPT; ++k)
        pbase[q0 + k * 256] = qsq[k] + mn[k];
}

// 640 blocks: 64 queries/block, 4 lanes per query split over chunks.
// Blocks 0..511 = dir1 (32 chunks), 512..639 = dir2 (128 chunks).
__global__ __launch_bounds__(256) void reduce_kernel(
    const float* __restrict__ pw, float* __restrict__ psum)
{
    const int blk = blockIdx.x, tid = threadIdx.x;
    const int sub = tid & 3, qi = tid >> 2;       // 4 lanes per query

    float m = BIGF;
    if (blk < 512) {                              // dir1: 8 loads/lane
        const int b  = blk >> 7;
        const int ql = ((blk & 127) << 6) + qi;
        const float* p = pw + (size_t)b * 32 * 8192 + ql;
        #pragma unroll
        for (int i = 0; i < 8; ++i)
            m = fminf(m, p[(sub * 8 + i) * 8192]);
    } else {                                      // dir2: 32 loads/lane
        const int z  = blk - 512;
        const int b  = z >> 5;
        const int ql = ((z & 31) << 6) + qi;
        const float* p = pw + P2_OFF + (size_t)b * 128 * 2048 + ql;
        #pragma unroll
        for (int i = 0; i < 32; ++i)
            m = fminf(m, p[(sub * 32 + i) * 2048]);
    }

    // Min across the 4-lane group, clamp, keep one copy.
    m = fminf(m, __shfl_xor(m, 1));
    m = fminf(m, __shfl_xor(m, 2));
    float s = (sub == 0) ? fmaxf(m, 0.0f) : 0.0f;

    // Wave + block sum.
    #pragma unroll
    for (int off = 32; off > 0; off >>= 1)
        s += __shfl_down(s, off);

    __shared__ float wsum[4];
    const int lane = tid & 63, w = tid >> 6;
    if (lane == 0) wsum[w] = s;
    __syncthreads();
    if (tid == 0) psum[blk] = (wsum[0] + wsum[1]) + (wsum[2] + wsum[3]);
}

__global__ __launch_bounds__(256) void final_kernel(
    const float* __restrict__ psum, float* __restrict__ out)
{
    float s = psum[threadIdx.x] + psum[threadIdx.x + 256];
    if (threadIdx.x < 128) s += psum[threadIdx.x + 512];

    #pragma unroll
    for (int off = 32; off > 0; off >>= 1)
        s += __shfl_down(s, off);

    __shared__ float wsum[4];
    const int lane = threadIdx.x & 63, w = threadIdx.x >> 6;
    if (lane == 0) wsum[w] = s;
    __syncthreads();
    if (threadIdx.x == 0)
        out[0] = ((wsum[0] + wsum[1]) + (wsum[2] + wsum[3])) * 1.0e-4f;
}

extern "C" void kernel_launch(void* const* d_in, const int* in_sizes, int n_in,
                              void* d_out, int out_size, void* d_ws, size_t ws_size,
                              hipStream_t stream) {
    const float* shape = (const float*)d_in[0];   // [4, 8192, 3]
    const float* skel  = (const float*)d_in[1];   // [4, 2048, 3]
    float* out         = (float*)d_out;           // scalar f32
    float* pw          = (float*)d_ws;

    // 256 tiles/batch x 4 batches = 1024 blocks (4/CU, 4 waves/SIMD).
    chamfer_kernel<<<dim3(256, 4), 256, 0, stream>>>(shape, skel, pw);

    // 640 blocks, then tiny deterministic final sum.
    reduce_kernel<<<RBLOCKS, 256, 0, stream>>>(pw, pw + PSUM_OFF);
    final_kernel<<<1, 256, 0, stream>>>(pw + PSUM_OFF, out);
}

// Round 14
// 24.192 us; speedup vs baseline: 5.6045x; 1.0781x over previous
//
#include <hip/hip_runtime.h>

// Bidirectional Chamfer loss, fused:
//   out = 1e-4 * ( sum_n min_m |shape[b,n]-skel[b,m]|^2
//                + sum_m min_n |skel[b,m]-shape[b,n]|^2 )
//
// R14: operand-pipe scoreboard: LDS(24.3) < VMEM(26.1) < s_load(29.0);
// R11 measured chamfer = VALU(6.0) + LDS(5.1) SUMMED -> convoy effect:
// phase-locked waves burst-issue reads at a ~86%-loaded LDS pipe.
// Only QPT reduces pipe DEMAND (R6: QPT 8->4 doubled it, regressed on
// model). This round: QPT=16 -> LDS reads/pair halved (pipe load ~43%).
// dir2 (2048 q = 128 threads x 16): each half-block owns its own target
// chunk. Partials layout unchanged -> reduce/final identical to R7.

#define QPT    16     // query points per thread
#define BIGF   3.4e38f

// ws layout (floats):
//  dir1 partials [b][ch][q] : 4 x 32 x 8192 = 1,048,576
//  dir2 partials [b][ch][q] : 4 x 128 x 2048 = 1,048,576 (at P2_OFF)
//  psum: RBLOCKS floats at PSUM_OFF
#define P2_OFF   1048576
#define PSUM_OFF 2097152
#define RBLOCKS  640

// Grid: 128 tiles/batch = 64 dir1 (2 qb x 32 ch) + 64 dir2 (chunk pairs).
// 512 blocks, 256 thr: 2 blocks/CU, 2 waves/SIMD, ~100 VGPR.
__global__ __launch_bounds__(256) void chamfer_kernel(
    const float* __restrict__ shape,  // [4, 8192, 3]
    const float* __restrict__ skel,   // [4, 2048, 3]
    float* __restrict__ pw)           // partial mins
{
    const int b   = blockIdx.y;
    const int tid = threadIdx.x;

    const float* q; const float* t; float* pbase;
    const float* ssrc;                // staging source (target points)
    int q0, qstride, lbase, scount;
    int x = blockIdx.x;
    if (x < 64) {                     // dir1: shape -> skel
        q = shape; t = skel;
        const int qb = x >> 5, ch = x & 31;
        pbase   = pw + ((size_t)b * 32 + ch) * 8192;
        q0      = qb * 4096 + tid;    // queries q0 + k*256, k<16
        qstride = 256;
        lbase   = 0;
        scount  = 64;
        ssrc    = t + ((size_t)b * 2048 + ch * 64) * 3;
        q       = shape + (size_t)b * 8192 * 3;
    } else {                          // dir2: skel -> shape
        const int z    = x - 64;      // chunk-pair index (0..63)
        const int half = tid >> 7;    // 0/1: which chunk this half-block owns
        const int ch   = 2 * z + half;
        pbase   = pw + P2_OFF + ((size_t)b * 128 + ch) * 2048;
        q0      = tid & 127;          // queries q0 + k*128, k<16
        qstride = 128;
        lbase   = half * 64;
        scount  = 128;
        ssrc    = shape + ((size_t)b * 8192 + z * 128) * 3;
        q       = skel + (size_t)b * 2048 * 3;
    }

    __shared__ float4 lds[128];

    // Stage targets as (x, y, z, |t|^2). dir1: 64, dir2: 128 (two chunks).
    if (tid < scount) {
        float tx = ssrc[tid * 3 + 0], ty = ssrc[tid * 3 + 1], tz = ssrc[tid * 3 + 2];
        lds[tid] = make_float4(tx, ty, tz, tx * tx + ty * ty + tz * tz);
    }

    // My QPT query points: precompute -2q and |q|^2.
    const float* qp = q + (size_t)q0 * 3;
    const int qs3 = qstride * 3;
    float nqx[QPT], nqy[QPT], nqz[QPT], qsq[QPT], mn[QPT];
    #pragma unroll
    for (int k = 0; k < QPT; ++k) {
        float xq = qp[k * qs3 + 0];
        float yq = qp[k * qs3 + 1];
        float zq = qp[k * qs3 + 2];
        nqx[k] = -2.0f * xq; nqy[k] = -2.0f * yq; nqz[k] = -2.0f * zq;
        qsq[k] = xq * xq + yq * yq + zq * zq;
        mn[k]  = BIGF;
    }

    __syncthreads();

    // Scan my 64 targets: per 2 targets & query -> 6 FMA + 1 v_min3_f32.
    // One broadcast ds_read_b128 now feeds 16 queries (was 8).
    #pragma unroll 2
    for (int j = 0; j < 64; j += 2) {
        float4 ta = lds[lbase + j + 0];           // broadcast: conflict-free
        float4 tb = lds[lbase + j + 1];
        #pragma unroll
        for (int k = 0; k < QPT; ++k) {
            float e0 = fmaf(nqx[k], ta.x,
                       fmaf(nqy[k], ta.y,
                       fmaf(nqz[k], ta.z, ta.w)));
            float e1 = fmaf(nqx[k], tb.x,
                       fmaf(nqy[k], tb.y,
                       fmaf(nqz[k], tb.z, tb.w)));
            mn[k] = fminf(fminf(mn[k], e0), e1);  // v_min3_f32
        }
    }

    // One coalesced store per (query, chunk) partial — no atomics.
    #pragma unroll
    for (int k = 0; k < QPT; ++k)
        pbase[q0 + k * qstride] = qsq[k] + mn[k];
}

// 640 blocks: 64 queries/block, 4 lanes per query split over chunks.
// Blocks 0..511 = dir1 (32 chunks), 512..639 = dir2 (128 chunks).
__global__ __launch_bounds__(256) void reduce_kernel(
    const float* __restrict__ pw, float* __restrict__ psum)
{
    const int blk = blockIdx.x, tid = threadIdx.x;
    const int sub = tid & 3, qi = tid >> 2;       // 4 lanes per query

    float m = BIGF;
    if (blk < 512) {                              // dir1: 8 loads/lane
        const int b  = blk >> 7;
        const int ql = ((blk & 127) << 6) + qi;
        const float* p = pw + (size_t)b * 32 * 8192 + ql;
        #pragma unroll
        for (int i = 0; i < 8; ++i)
            m = fminf(m, p[(sub * 8 + i) * 8192]);
    } else {                                      // dir2: 32 loads/lane
        const int z  = blk - 512;
        const int b  = z >> 5;
        const int ql = ((z & 31) << 6) + qi;
        const float* p = pw + P2_OFF + (size_t)b * 128 * 2048 + ql;
        #pragma unroll
        for (int i = 0; i < 32; ++i)
            m = fminf(m, p[(sub * 32 + i) * 2048]);
    }

    // Min across the 4-lane group, clamp, keep one copy.
    m = fminf(m, __shfl_xor(m, 1));
    m = fminf(m, __shfl_xor(m, 2));
    float s = (sub == 0) ? fmaxf(m, 0.0f) : 0.0f;

    // Wave + block sum.
    #pragma unroll
    for (int off = 32; off > 0; off >>= 1)
        s += __shfl_down(s, off);

    __shared__ float wsum[4];
    const int lane = tid & 63, w = tid >> 6;
    if (lane == 0) wsum[w] = s;
    __syncthreads();
    if (tid == 0) psum[blk] = (wsum[0] + wsum[1]) + (wsum[2] + wsum[3]);
}

__global__ __launch_bounds__(256) void final_kernel(
    const float* __restrict__ psum, float* __restrict__ out)
{
    float s = psum[threadIdx.x] + psum[threadIdx.x + 256];
    if (threadIdx.x < 128) s += psum[threadIdx.x + 512];

    #pragma unroll
    for (int off = 32; off > 0; off >>= 1)
        s += __shfl_down(s, off);

    __shared__ float wsum[4];
    const int lane = threadIdx.x & 63, w = threadIdx.x >> 6;
    if (lane == 0) wsum[w] = s;
    __syncthreads();
    if (threadIdx.x == 0)
        out[0] = ((wsum[0] + wsum[1]) + (wsum[2] + wsum[3])) * 1.0e-4f;
}

extern "C" void kernel_launch(void* const* d_in, const int* in_sizes, int n_in,
                              void* d_out, int out_size, void* d_ws, size_t ws_size,
                              hipStream_t stream) {
    const float* shape = (const float*)d_in[0];   // [4, 8192, 3]
    const float* skel  = (const float*)d_in[1];   // [4, 2048, 3]
    float* out         = (float*)d_out;           // scalar f32
    float* pw          = (float*)d_ws;

    // 128 tiles/batch x 4 batches = 512 blocks (2/CU, 2 waves/SIMD).
    chamfer_kernel<<<dim3(128, 4), 256, 0, stream>>>(shape, skel, pw);

    // 640 blocks, then tiny deterministic final sum.
    reduce_kernel<<<RBLOCKS, 256, 0, stream>>>(pw, pw + PSUM_OFF);
    final_kernel<<<1, 256, 0, stream>>>(pw + PSUM_OFF, out);
}